// Round 2
// baseline (285.965 us; speedup 1.0000x reference)
//
#include <hip/hip_runtime.h>
#include <stdint.h>

typedef _Float16 f16;
typedef f16 f16x4 __attribute__((ext_vector_type(4)));
typedef f16 f16x8 __attribute__((ext_vector_type(8)));
typedef float f32x4 __attribute__((ext_vector_type(4)));

constexpr float SCALE = 0.08838834764831845f; // 1/sqrt(128)

__device__ __forceinline__ void glds16(const f16* g, f16* l) {
  __builtin_amdgcn_global_load_lds(
      (const __attribute__((address_space(1))) void*)g,
      (__attribute__((address_space(3))) void*)l, 16, 0, 0);
}

// ---------------- projection:
// q = f1*W1^T + b1 (f16), k = f2*W2^T + b2 (f16)
// also writes f1t/f2t = f16 TRANSPOSED features [B,128,1024] (PV B-operand layout)
__global__ __launch_bounds__(256) void proj_kernel(
    const float* __restrict__ f1, const float* __restrict__ f2,
    const float* __restrict__ W1, const float* __restrict__ b1,
    const float* __restrict__ W2, const float* __restrict__ b2,
    f16* __restrict__ q_h, f16* __restrict__ k_h,
    f16* __restrict__ f1t, f16* __restrict__ f2t)
{
  __shared__ f16 a_lds[128 * 128]; // feature tile, chunk-XOR swizzled
  __shared__ f16 w_lds[128 * 128]; // W row-major [out][in], swizzled

  const int tid = threadIdx.x;
  const int blk = blockIdx.x;
  const bool qside = blk < 512;
  const float* feat = qside ? f1 : f2;
  const float* W    = qside ? W1 : W2;
  const float* bias = qside ? b1 : b2;
  f16* op = qside ? q_h : k_h;
  f16* ft = qside ? f1t : f2t;
  const size_t row0 = (size_t)(qside ? blk : blk - 512) * 128;

  for (int it = 0; it < 16; ++it) {
    int u = tid + it * 256;
    int r = u >> 5;
    int c4 = (u & 31) * 4;
    float4 v = *(const float4*)&feat[(row0 + r) * 128 + c4];
    f16x4 h4 = { (f16)v.x, (f16)v.y, (f16)v.z, (f16)v.w };
    int adr = r * 128 + ((((c4 >> 3) ^ (r & 7)) << 3) | (c4 & 7));
    *(f16x4*)&a_lds[adr] = h4;
    float4 wv = *(const float4*)&W[r * 128 + c4];
    f16x4 wh = { (f16)wv.x, (f16)wv.y, (f16)wv.z, (f16)wv.w };
    *(f16x4*)&w_lds[adr] = wh;
  }
  __syncthreads();

  const int w = tid >> 6, l = tid & 63, lam = l & 15, g = l >> 4;
  f32x4 acc[2][8] = {};
#pragma unroll
  for (int kc = 0; kc < 4; ++kc) {
    f16x8 a[2];
#pragma unroll
    for (int rf = 0; rf < 2; ++rf) {
      int ar = w * 32 + rf * 16 + lam;
      a[rf] = *(const f16x8*)&a_lds[ar * 128 + (((4 * kc + g) ^ (ar & 7)) << 3)];
    }
#pragma unroll
    for (int cf = 0; cf < 8; ++cf) {
      int br = cf * 16 + lam;
      f16x8 bfr = *(const f16x8*)&w_lds[br * 128 + (((4 * kc + g) ^ (br & 7)) << 3)];
      acc[0][cf] = __builtin_amdgcn_mfma_f32_16x16x32_f16(a[0], bfr, acc[0][cf], 0, 0, 0);
      acc[1][cf] = __builtin_amdgcn_mfma_f32_16x16x32_f16(a[1], bfr, acc[1][cf], 0, 0, 0);
    }
  }
#pragma unroll
  for (int cf = 0; cf < 8; ++cf) {
    int col = cf * 16 + lam;
    float bv = bias[col];
#pragma unroll
    for (int rf = 0; rf < 2; ++rf)
#pragma unroll
      for (int i = 0; i < 4; ++i) {
        size_t grow = row0 + w * 32 + rf * 16 + g * 4 + i;
        op[grow * 128 + col] = (f16)(acc[rf][cf][i] + bv);
      }
  }

  // transposed feature write: ft[b][f][l], read columns from a_lds
  {
    const int b = (int)(row0 >> 10);
    const int l0 = (int)(row0 & 1023);
    const int f = tid >> 1;
    const int half = tid & 1;
    f16 buf[64];
#pragma unroll
    for (int j = 0; j < 64; ++j) {
      int r = half * 64 + j;
      buf[j] = a_lds[r * 128 + ((((f >> 3) ^ (r & 7)) << 3) | (f & 7))];
    }
    f16* dst = ft + ((size_t)b * 128 + f) * 1024 + l0 + half * 64;
#pragma unroll
    for (int c = 0; c < 8; ++c)
      *(f16x8*)&dst[c * 8] = *(const f16x8*)&buf[c * 8];
  }
}

// ---------------- flash attention pass
// PASS 0: Q=q, K=k, Vt=f2t, mask[b][l=qrow][m=kvcol], writes out2
// PASS 1: Q=k, K=q, Vt=f1t, mask[b][l=kvcol][m=qrow], writes out1
template <int PASS>
__global__ __launch_bounds__(256) void attn_kernel(
    const f16* __restrict__ Qh, const f16* __restrict__ Kh, const f16* __restrict__ Vt,
    const int* __restrict__ mask, float* __restrict__ outp)
{
  __shared__ f16 q_lds[64 * 128];
  __shared__ f16 k_lds[64 * 128];
  __shared__ f16 v_lds[128 * 64];     // V^T tile: [feature][kv], swizzled
  __shared__ f16 p_lds[4 * 16 * 72];  // per-wave P, pitch 72
  __shared__ uint32_t mbits[128];     // [64 rows][2 words of 32 cols]

  const int tid = threadIdx.x;
  const int u = blockIdx.x;
  const int xcd = u & 7;
  const int jj = u >> 3;
  const int qt = jj & 15;
  const int b = ((jj >> 4) << 3) | xcd;

  const int w = tid >> 6, l = tid & 63, lam = l & 15, g = l >> 4;
  const size_t batch_row = (size_t)b * 1024;

  // stage Q tile once (64 rows x 128, chunk-XOR swizzle via pre-swizzled source)
  {
    const f16* qbase = Qh + (batch_row + (size_t)qt * 64) * 128;
    for (int it = 0; it < 4; ++it) {
      int slot0 = (w * 4 + it) * 64;
      int i = slot0 + l;
      int r = i >> 4, ch = i & 15;
      glds16(qbase + r * 128 + ((ch ^ (r & 7)) << 3), q_lds + slot0 * 8);
    }
  }

  f32x4 acc[8] = {};
  float mrun[4], lrun[4];
#pragma unroll
  for (int i = 0; i < 4; ++i) { mrun[i] = -__builtin_inff(); lrun[i] = 0.f; }

  const f16* vtb = Vt + (size_t)b * 131072;

  for (int kt = 0; kt < 16; ++kt) {
    __syncthreads();
    const int kb = kt * 64;
    // stage K tile (64 rows x 128, swizzled)
    const f16* kbase = Kh + (batch_row + kb) * 128;
    for (int it = 0; it < 4; ++it) {
      int slot0 = (w * 4 + it) * 64;
      int i = slot0 + l;
      int r = i >> 4, ch = i & 15;
      glds16(kbase + r * 128 + ((ch ^ (r & 7)) << 3), k_lds + slot0 * 8);
    }
    // stage V^T tile (128 feature-rows x 64 kv-cols, swizzled)
    for (int it = 0; it < 4; ++it) {
      int slot0 = (w * 4 + it) * 64;
      int i = slot0 + l;
      int r = i >> 3, ch = i & 7;
      glds16(vtb + r * 1024 + kb + ((ch ^ (r & 7)) << 3), v_lds + slot0 * 8);
    }
    // stage mask bits for this 64x64 tile
    if (tid < 128) {
      int jr = tid >> 1, half = tid & 1;
      int l0 = (PASS == 0) ? qt * 64 : kb;
      int m0 = (PASS == 0) ? kb : qt * 64;
      const int4* src = (const int4*)(mask + (batch_row + l0 + jr) * 1024 + m0 + half * 32);
      uint32_t wd = 0;
#pragma unroll
      for (int e = 0; e < 8; ++e) {
        int4 v = src[e];
        if (v.x != 0) wd |= 1u << (e * 4 + 0);
        if (v.y != 0) wd |= 1u << (e * 4 + 1);
        if (v.z != 0) wd |= 1u << (e * 4 + 2);
        if (v.w != 0) wd |= 1u << (e * 4 + 3);
      }
      mbits[jr * 2 + half] = wd;
    }
    __syncthreads();

    // QK^T : S[16 rows of this wave x 64 kv]
    f32x4 sv[4] = {};
#pragma unroll
    for (int kc = 0; kc < 4; ++kc) {
      int ar = w * 16 + lam;
      f16x8 aq = *(const f16x8*)&q_lds[ar * 128 + (((4 * kc + g) ^ (ar & 7)) << 3)];
#pragma unroll
      for (int cf = 0; cf < 4; ++cf) {
        int br = cf * 16 + lam;
        f16x8 bk = *(const f16x8*)&k_lds[br * 128 + (((4 * kc + g) ^ (br & 7)) << 3)];
        sv[cf] = __builtin_amdgcn_mfma_f32_16x16x32_f16(aq, bk, sv[cf], 0, 0, 0);
      }
    }

    // gather mask bits: bit (cf*4+i) of mk for D element (row=g*4+i, col=cf*16+lam)
    uint32_t mk = 0;
    if constexpr (PASS == 0) {
#pragma unroll
      for (int i = 0; i < 4; ++i) {
        uint32_t w0 = mbits[(w * 16 + g * 4 + i) * 2 + 0];
        uint32_t w1 = mbits[(w * 16 + g * 4 + i) * 2 + 1];
#pragma unroll
        for (int cf = 0; cf < 4; ++cf) {
          uint32_t wd = (cf < 2) ? w0 : w1;
          mk |= ((wd >> ((cf & 1) * 16 + lam)) & 1u) << (cf * 4 + i);
        }
      }
    } else {
#pragma unroll
      for (int cf = 0; cf < 4; ++cf) {
        uint32_t wd = mbits[(cf * 16 + lam) * 2 + (w >> 1)];
#pragma unroll
        for (int i = 0; i < 4; ++i)
          mk |= ((wd >> ((w & 1) * 16 + g * 4 + i)) & 1u) << (cf * 4 + i);
      }
    }

    // online softmax over kv columns
    float mrow[4];
#pragma unroll
    for (int i = 0; i < 4; ++i) mrow[i] = -1e30f;
#pragma unroll
    for (int cf = 0; cf < 4; ++cf)
#pragma unroll
      for (int i = 0; i < 4; ++i) {
        float v = sv[cf][i] * SCALE;
        sv[cf][i] = v;
        mrow[i] = fmaxf(mrow[i], ((mk >> (cf * 4 + i)) & 1u) ? v : -1e30f);
      }
#pragma unroll
    for (int d = 1; d <= 8; d <<= 1)
#pragma unroll
      for (int i = 0; i < 4; ++i)
        mrow[i] = fmaxf(mrow[i], __shfl_xor(mrow[i], d, 64));

    float sf[4], lsum[4];
#pragma unroll
    for (int i = 0; i < 4; ++i) {
      float mn = fmaxf(mrun[i], mrow[i]);
      sf[i] = __expf(mrun[i] - mn);
      mrun[i] = mn;
      lsum[i] = 0.f;
    }
#pragma unroll
    for (int cf = 0; cf < 4; ++cf)
#pragma unroll
      for (int i = 0; i < 4; ++i) {
        float p = ((mk >> (cf * 4 + i)) & 1u) ? __expf(sv[cf][i] - mrun[i]) : 0.f;
        lsum[i] += p;
        int row = g * 4 + i;
        int cchunk = 2 * cf + (lam >> 3);
        p_lds[w * 1152 + row * 72 + (((cchunk ^ (row & 7)) << 3) | (lam & 7))] = (f16)p;
      }
#pragma unroll
    for (int d = 1; d <= 8; d <<= 1)
#pragma unroll
      for (int i = 0; i < 4; ++i)
        lsum[i] += __shfl_xor(lsum[i], d, 64);
#pragma unroll
    for (int i = 0; i < 4; ++i) lrun[i] = lrun[i] * sf[i] + lsum[i];
#pragma unroll
    for (int nf = 0; nf < 8; ++nf)
#pragma unroll
      for (int i = 0; i < 4; ++i) acc[nf][i] *= sf[i];

    // PV: O[16 x 128] += P[16 x 64] * V[64 x 128]  (V read as V^T rows)
#pragma unroll
    for (int kc2 = 0; kc2 < 2; ++kc2) {
      f16x8 ap = *(const f16x8*)&p_lds[w * 1152 + lam * 72 + (((4 * kc2 + g) ^ (lam & 7)) << 3)];
#pragma unroll
      for (int nf = 0; nf < 8; ++nf) {
        int vr = nf * 16 + lam;
        f16x8 bv = *(const f16x8*)&v_lds[vr * 64 + (((kc2 * 4 + g) ^ (vr & 7)) << 3)];
        acc[nf] = __builtin_amdgcn_mfma_f32_16x16x32_f16(ap, bv, acc[nf], 0, 0, 0);
      }
    }
  }

  // epilogue: divide by row sums, write f32
  float inv[4];
#pragma unroll
  for (int i = 0; i < 4; ++i) inv[i] = (lrun[i] > 0.f) ? 1.f / lrun[i] : 0.f;
  const size_t orow0 = batch_row + (size_t)qt * 64 + w * 16;
#pragma unroll
  for (int nf = 0; nf < 8; ++nf)
#pragma unroll
    for (int i = 0; i < 4; ++i)
      outp[(orow0 + g * 4 + i) * 128 + nf * 16 + lam] = acc[nf][i] * inv[i];
}

extern "C" void kernel_launch(void* const* d_in, const int* in_sizes, int n_in,
                              void* d_out, int out_size, void* d_ws, size_t ws_size,
                              hipStream_t stream) {
  const float* f1 = (const float*)d_in[0];
  const float* f2 = (const float*)d_in[1];
  const int* mask = (const int*)d_in[2];
  const float* W1 = (const float*)d_in[3];
  const float* b1 = (const float*)d_in[4];
  const float* W2 = (const float*)d_in[5];
  const float* b2 = (const float*)d_in[6];
  float* out = (float*)d_out;

  if (ws_size < (size_t)4 * 8388608 * sizeof(f16)) return; // need 64 MiB scratch

  f16* q_h  = (f16*)d_ws;
  f16* k_h  = q_h + 8388608;
  f16* f1t  = k_h + 8388608;
  f16* f2t  = f1t + 8388608;

  proj_kernel<<<1024, 256, 0, stream>>>(f1, f2, W1, b1, W2, b2, q_h, k_h, f1t, f2t);
  // out = (out1 [B,L2,F1], out2 [B,L1,F2]) concatenated flat
  attn_kernel<0><<<1024, 256, 0, stream>>>(q_h, k_h, f2t, mask, out + 8388608); // out2
  attn_kernel<1><<<1024, 256, 0, stream>>>(k_h, q_h, f1t, mask, out);           // out1
}